// Round 5
// baseline (1346.634 us; speedup 1.0000x reference)
//
#include <hip/hip_runtime.h>
#include <hip/hip_bf16.h>

#define N_ 50000
#define E_ 1000000
#define R_ 16
#define NB_ 16
#define D_ 128
#define L_ 3
#define G_ 64
#define M_SEG (N_*R_)          // 800000 segments
#define KTOT ((R_+1)*D_)       // 2176
#define SCAN_BLOCKS ((M_SEG + 1023)/1024)   // 782
#define MAXM 450000            // cap on multi-edge segments (actual ~285k)
#define GM 64                  // GEMM M-tile (nodes per block)

typedef _Float16 f16;
typedef _Float16 f16x8 __attribute__((ext_vector_type(8)));
typedef _Float16 f16x4 __attribute__((ext_vector_type(4)));
typedef float f32x4 __attribute__((ext_vector_type(4)));

// ---------------- CSR build ----------------

__global__ __launch_bounds__(256) void k_hist(const int* __restrict__ ei, const int* __restrict__ et,
                                              int* __restrict__ cnt){
  int e = blockIdx.x*256 + threadIdx.x;
  if (e < E_){
    int seg = ei[E_ + e]*R_ + et[e];     // dst*R + type
    atomicAdd(&cnt[seg], 1);
  }
}

__global__ __launch_bounds__(256) void k_scan_sum(const int* __restrict__ cnt, int* __restrict__ bsum){
  __shared__ int sh[256];
  int base = blockIdx.x*1024 + threadIdx.x*4;
  int s = 0;
  #pragma unroll
  for (int j=0;j<4;++j){ int i = base + j; if (i < M_SEG) s += cnt[i]; }
  sh[threadIdx.x] = s; __syncthreads();
  for (int off=128; off>0; off>>=1){
    if (threadIdx.x < off) sh[threadIdx.x] += sh[threadIdx.x+off];
    __syncthreads();
  }
  if (threadIdx.x==0) bsum[blockIdx.x] = sh[0];
}

__global__ __launch_bounds__(256) void k_scan_off(const int* __restrict__ bsum, int* __restrict__ boff){
  __shared__ int sh[256];
  int tid = threadIdx.x;
  int v[4]; int ts = 0;
  #pragma unroll
  for (int j=0;j<4;++j){ int i = tid*4+j; v[j] = (i<SCAN_BLOCKS)? bsum[i] : 0; ts += v[j]; }
  sh[tid] = ts; __syncthreads();
  for (int off=1; off<256; off<<=1){
    int a = sh[tid];
    int b = (tid>=off)? sh[tid-off] : 0;
    __syncthreads(); sh[tid] = a + b; __syncthreads();
  }
  int excl = sh[tid] - ts;
  #pragma unroll
  for (int j=0;j<4;++j){ int i = tid*4+j; if (i<SCAN_BLOCKS) boff[i] = excl; excl += v[j]; }
}

__global__ __launch_bounds__(256) void k_scan_write(const int* __restrict__ cnt, const int* __restrict__ boff,
                                                    int* __restrict__ row_ptr, int* __restrict__ cursor){
  __shared__ int sh[256];
  int tid = threadIdx.x;
  int base = blockIdx.x*1024 + tid*4;
  int v[4]; int ts = 0;
  #pragma unroll
  for (int j=0;j<4;++j){ int i = base+j; v[j] = (i<M_SEG)? cnt[i] : 0; ts += v[j]; }
  sh[tid] = ts; __syncthreads();
  for (int off=1; off<256; off<<=1){
    int a = sh[tid];
    int b = (tid>=off)? sh[tid-off] : 0;
    __syncthreads(); sh[tid] = a + b; __syncthreads();
  }
  int excl = boff[blockIdx.x] + sh[tid] - ts;
  #pragma unroll
  for (int j=0;j<4;++j){
    int i = base+j;
    if (i < M_SEG){
      row_ptr[i] = excl; cursor[i] = excl;
      if (i == M_SEG-1) row_ptr[M_SEG] = excl + v[j];
    }
    excl += v[j];
  }
}

__global__ __launch_bounds__(256) void k_place(const int* __restrict__ ei, const int* __restrict__ et,
                                               int* __restrict__ cursor, int* __restrict__ csr_src){
  int e = blockIdx.x*256 + threadIdx.x;
  if (e < E_){
    int seg = ei[E_+e]*R_ + et[e];
    int pos = atomicAdd(&cursor[seg], 1);
    csr_src[pos] = ei[e];                 // src node id, grouped by (dst,rel)
  }
}

// idxT[r*N + n]: encoded A-row pointer. bit0: 0 -> x16 table, 1 -> abuf table. val>>1 = row.
// empty -> abuf row 0 (zeros); degree-1 -> x16[src]; multi -> abuf[1+slot]; root (r=16) -> x16[n].
// For multi segments, also emit flat worklists mp0/mpc/minv (kills the pointer chain in k_means).
__global__ __launch_bounds__(256) void k_idx(const int* __restrict__ cnt, const int* __restrict__ row_ptr,
                                             const int* __restrict__ csr_src,
                                             int* __restrict__ idxT, int* __restrict__ mp0,
                                             int* __restrict__ mpc, float* __restrict__ minv,
                                             int* __restrict__ mcount){
  int i = blockIdx.x*256 + threadIdx.x;
  if (i < M_SEG){
    int n = i >> 4, r = i & 15;
    int c = cnt[i];
    int v;
    if (c == 0) v = 1;
    else if (c == 1) v = csr_src[row_ptr[i]] << 1;
    else {
      int slot = atomicAdd(mcount, 1);
      if (slot < MAXM){
        mp0[slot] = row_ptr[i]; mpc[slot] = c; minv[slot] = 1.0f/(float)c;
        v = ((1 + slot) << 1) | 1;
      }
      else v = 1;
    }
    idxT[r*N_ + n] = v;
  } else if (i < M_SEG + N_){
    int n = i - M_SEG;
    idxT[16*N_ + n] = n << 1;            // root slot
  }
}

// ---------------- input staging ----------------

__global__ __launch_bounds__(128) void k_gather(const int* __restrict__ ids, const float* __restrict__ emb,
                                                float* __restrict__ x, f16* __restrict__ x16){
  int t = threadIdx.x;
  int n = blockIdx.x*4 + (t >> 5);
  int c = (t & 31) * 4;
  if (n < N_){
    int id = ids[n];
    float4 v = *(const float4*)(emb + (size_t)id*D_ + c);
    *(float4*)(x + (size_t)n*D_ + c) = v;
    f16x4 h = {(f16)v.x, (f16)v.y, (f16)v.z, (f16)v.w};
    *(f16x4*)(x16 + (size_t)n*D_ + c) = h;
  }
}

// Wt[l][o][kk] (f16, K-major rows): kk = r*128 + i holds W_r[i][o]; r==16 block holds root[i][o]
__global__ __launch_bounds__(128) void k_wprep(const float* __restrict__ comp, const float* __restrict__ basis,
                                               const float* __restrict__ root, f16* __restrict__ Wt){
  int b = blockIdx.x;
  int o = threadIdx.x;
  int l = b / ((R_+1)*D_);
  int rem = b % ((R_+1)*D_);
  int r = rem / D_;
  int i = rem % D_;
  float acc = 0.f;
  if (r < R_){
    #pragma unroll
    for (int bb=0; bb<NB_; ++bb)
      acc += comp[(l*R_+r)*NB_+bb] * basis[((l*NB_+bb)*D_+i)*D_+o];
  } else {
    acc = root[(l*D_+i)*D_+o];
  }
  Wt[(size_t)l*D_*KTOT + (size_t)o*KTOT + r*D_ + i] = (f16)acc;
}

// ---------------- per-layer: multi-edge segment means ----------------
// one 16-lane group per multi-edge segment (f16x8 per lane), grid-stride, edge loop 2x unrolled.
// 4 segments in flight per wave; flat mp0/mpc/minv worklists (no row_ptr chain).
__global__ __launch_bounds__(256) void k_means(const f16* __restrict__ x16,
                                               const int* __restrict__ csr_src,
                                               const int* __restrict__ mp0, const int* __restrict__ mpc,
                                               const float* __restrict__ minv, const int* __restrict__ mcount,
                                               f16* __restrict__ abuf){
  int grp = (blockIdx.x*256 + threadIdx.x) >> 4;
  int l16 = threadIdx.x & 15;
  int mc = *mcount; if (mc > MAXM) mc = MAXM;
  int ngrp = gridDim.x * 16;
  for (int slot = grp; slot < mc; slot += ngrp){
    int p0 = mp0[slot];
    int c  = mpc[slot];
    float ic = minv[slot];
    int p1 = p0 + c;
    float a0=0.f,a1=0.f,a2=0.f,a3=0.f,a4=0.f,a5=0.f,a6=0.f,a7=0.f;
    float b0=0.f,b1=0.f,b2=0.f,b3=0.f,b4=0.f,b5=0.f,b6=0.f,b7=0.f;
    int p = p0;
    for (; p + 1 < p1; p += 2){
      int s0 = csr_src[p], s1 = csr_src[p+1];
      f16x8 v0 = *(const f16x8*)(x16 + (size_t)s0*D_ + l16*8);
      f16x8 v1 = *(const f16x8*)(x16 + (size_t)s1*D_ + l16*8);
      a0+=(float)v0[0]; a1+=(float)v0[1]; a2+=(float)v0[2]; a3+=(float)v0[3];
      a4+=(float)v0[4]; a5+=(float)v0[5]; a6+=(float)v0[6]; a7+=(float)v0[7];
      b0+=(float)v1[0]; b1+=(float)v1[1]; b2+=(float)v1[2]; b3+=(float)v1[3];
      b4+=(float)v1[4]; b5+=(float)v1[5]; b6+=(float)v1[6]; b7+=(float)v1[7];
    }
    if (p < p1){
      int s0 = csr_src[p];
      f16x8 v0 = *(const f16x8*)(x16 + (size_t)s0*D_ + l16*8);
      a0+=(float)v0[0]; a1+=(float)v0[1]; a2+=(float)v0[2]; a3+=(float)v0[3];
      a4+=(float)v0[4]; a5+=(float)v0[5]; a6+=(float)v0[6]; a7+=(float)v0[7];
    }
    f16x8 o = {(f16)((a0+b0)*ic),(f16)((a1+b1)*ic),(f16)((a2+b2)*ic),(f16)((a3+b3)*ic),
               (f16)((a4+b4)*ic),(f16)((a5+b5)*ic),(f16)((a6+b6)*ic),(f16)((a7+b7)*ic)};
    *(f16x8*)(abuf + (size_t)(1+slot)*D_ + l16*8) = o;
  }
}

// ---------------- per-layer: GEMM + LN + relu + residual ----------------
// block: 64 nodes x 128 cols, 256 threads (4 waves). Wave w owns cols [w*32, w*32+32),
// all 64 rows (4 m-tiles) -> each B fragment feeds 4 MFMAs. 782 blocks = 3 waves/SIMD.
// A via idxT-indexed global loads; B direct from L2-resident Wt; LN via LDS partials (1 barrier).
__global__ __launch_bounds__(256) void k_gemm(
    const int* __restrict__ idxT, const f16* __restrict__ x16, const f16* __restrict__ abuf,
    const f16* __restrict__ Wt, const float* __restrict__ xin,
    const float* __restrict__ bias, const float* __restrict__ gamma, const float* __restrict__ beta,
    float* __restrict__ xout, f16* __restrict__ xout16)
{
  __shared__ float2 part[GM][4];

  const int tid  = threadIdx.x;
  const int lane = tid & 63;
  const int wave = tid >> 6;
  const int l15  = lane & 15;
  const int quad = lane >> 4;
  const int nbase = blockIdx.x * GM;
  const int colb = wave * 32;

  f32x4 acc[4][2];
  f32x4 z = {0.f,0.f,0.f,0.f};
  #pragma unroll
  for (int h=0;h<4;++h){ acc[h][0] = z; acc[h][1] = z; }

  int nodeh[4];
  #pragma unroll
  for (int h=0;h<4;++h) nodeh[h] = nbase + h*16 + l15;

  // per-nt B pointers (walk +128 f16 per relation; ks offsets are compile-time)
  const f16* wp0 = Wt + (size_t)(colb + l15)*KTOT + quad*8;
  const f16* wp1 = Wt + (size_t)(colb + 16 + l15)*KTOT + quad*8;

  // prefetch relation-0 A indices
  int aidx[4];
  #pragma unroll
  for (int h=0;h<4;++h) aidx[h] = (nodeh[h] < N_) ? idxT[nodeh[h]] : 1;

  for (int r = 0; r < R_+1; ++r){
    const f16* ab[4];
    #pragma unroll
    for (int h=0;h<4;++h)
      ab[h] = ((aidx[h] & 1) ? abuf : x16) + (size_t)(aidx[h] >> 1) * D_ + quad*8;

    // prefetch next relation's A indices (hidden behind this relation's MFMAs)
    if (r < R_){
      #pragma unroll
      for (int h=0;h<4;++h) aidx[h] = (nodeh[h] < N_) ? idxT[(r+1)*N_ + nodeh[h]] : 1;
    }

    #pragma unroll
    for (int ks = 0; ks < 4; ++ks){
      f16x8 bf0 = *(const f16x8*)(wp0 + ks*32);
      f16x8 bf1 = *(const f16x8*)(wp1 + ks*32);
      #pragma unroll
      for (int h = 0; h < 4; ++h){
        f16x8 af = *(const f16x8*)(ab[h] + ks*32);
        acc[h][0] = __builtin_amdgcn_mfma_f32_16x16x32_f16(af, bf0, acc[h][0], 0, 0, 0);
        acc[h][1] = __builtin_amdgcn_mfma_f32_16x16x32_f16(af, bf1, acc[h][1], 0, 0, 0);
      }
    }
    wp0 += D_; wp1 += D_;
  }

  // epilogue: bias, then LN stats. Row's 128 cols are split across 4 waves -> LDS partials.
  float bv[2], gv[2], btv[2];
  #pragma unroll
  for (int nt=0;nt<2;++nt){
    int col = colb + nt*16 + l15;
    bv[nt] = bias[col]; gv[nt] = gamma[col]; btv[nt] = beta[col];
  }
  #pragma unroll
  for (int h=0;h<4;++h){
    #pragma unroll
    for (int j=0;j<4;++j){
      float t0 = acc[h][0][j] + bv[0];
      float t1 = acc[h][1][j] + bv[1];
      float s  = t0 + t1;
      float s2 = t0*t0 + t1*t1;
      #pragma unroll
      for (int m=1;m<16;m<<=1){ s += __shfl_xor(s,m,64); s2 += __shfl_xor(s2,m,64); }
      if (l15 == 0){
        int row = h*16 + quad*4 + j;     // C/D: col=lane&15, row=quad*4+reg
        part[row][wave] = make_float2(s, s2);
      }
    }
  }
  __syncthreads();
  #pragma unroll
  for (int h=0;h<4;++h){
    #pragma unroll
    for (int j=0;j<4;++j){
      int row = h*16 + quad*4 + j;
      int node = nbase + row;
      float2 p0 = part[row][0], p1 = part[row][1], p2 = part[row][2], p3 = part[row][3];
      float s  = p0.x + p1.x + p2.x + p3.x;
      float s2 = p0.y + p1.y + p2.y + p3.y;
      float mu  = s * (1.f/128.f);
      float var = s2 * (1.f/128.f) - mu*mu;
      float rs  = rsqrtf(var + 1e-5f);
      if (node < N_){
        #pragma unroll
        for (int nt=0;nt<2;++nt){
          int col = colb + nt*16 + l15;
          float v = acc[h][nt][j] + bv[nt];
          float o = (v-mu)*rs*gv[nt] + btv[nt];
          o = fmaxf(o, 0.f);
          float res = xin[(size_t)node*D_ + col] + o;
          xout[(size_t)node*D_ + col] = res;
          xout16[(size_t)node*D_ + col] = (f16)res;
        }
      }
    }
  }
}

// ---------------- outputs ----------------

__device__ __forceinline__ int lbound_batch(const int* __restrict__ b, int key){
  int lo=0, hi=N_;
  while (lo<hi){ int mid=(lo+hi)>>1; if (b[mid]<key) lo=mid+1; else hi=mid; }
  return lo;
}

__global__ __launch_bounds__(256) void k_pool(const float* __restrict__ x, const int* __restrict__ batch,
                                              float* __restrict__ gout){
  __shared__ float sh[256];
  int g = blockIdx.x;
  int a = lbound_batch(batch, g);
  int b = lbound_batch(batch, g+1);
  int t = threadIdx.x;
  int d = t & 127, half = t >> 7;
  float s = 0.f;
  for (int n = a + half; n < b; n += 2) s += x[(size_t)n*D_ + d];
  sh[t] = s; __syncthreads();
  if (half == 0){
    float tot = sh[t] + sh[t+128];
    int c = b - a;
    gout[g*D_ + d] = tot / (float)(c > 1 ? c : 1);
  }
}

// ---------------- launch ----------------

extern "C" void kernel_launch(void* const* d_in, const int* in_sizes, int n_in,
                              void* d_out, int out_size, void* d_ws, size_t ws_size,
                              hipStream_t stream){
  const int*   node_ids = (const int*)d_in[0];
  const int*   ei       = (const int*)d_in[1];   // [2,E]: row0=src, row1=dst
  const int*   et       = (const int*)d_in[2];
  const int*   batch    = (const int*)d_in[3];
  const float* emb      = (const float*)d_in[4];
  const float* comp     = (const float*)d_in[5];
  const float* basis    = (const float*)d_in[6];
  const float* root     = (const float*)d_in[7];
  const float* bias     = (const float*)d_in[8];
  const float* gamma    = (const float*)d_in[9];
  const float* beta     = (const float*)d_in[10];
  float* out = (float*)d_out;                    // [N*D] x, then [G*D] graph_embedding

  char* ws = (char*)d_ws;
  size_t off = 0;
  auto alloc = [&](size_t bytes) -> void* {
    void* p = ws + off;
    off = (off + bytes + 255) & ~(size_t)255;
    return p;
  };
  int*   cnt     = (int*)  alloc((size_t)M_SEG*4);
  int*   row_ptr = (int*)  alloc(((size_t)M_SEG+1)*4);
  int*   cursor  = (int*)  alloc((size_t)M_SEG*4);
  int*   csr_src = (int*)  alloc((size_t)E_*4);
  int*   bsum    = (int*)  alloc((size_t)SCAN_BLOCKS*4);
  int*   boff    = (int*)  alloc((size_t)SCAN_BLOCKS*4);
  int*   idxT    = (int*)  alloc((size_t)(R_+1)*N_*4);
  int*   mp0     = (int*)  alloc((size_t)MAXM*4);
  int*   mpc     = (int*)  alloc((size_t)MAXM*4);
  float* minv    = (float*)alloc((size_t)MAXM*4);
  int*   mcount  = (int*)  alloc(256);
  float* xA      = (float*)alloc((size_t)N_*D_*4);
  float* xB      = (float*)alloc((size_t)N_*D_*4);
  f16*   xA16    = (f16*)  alloc((size_t)N_*D_*2);
  f16*   xB16    = (f16*)  alloc((size_t)N_*D_*2);
  f16*   Wt      = (f16*)  alloc((size_t)L_*D_*KTOT*2);
  f16*   abuf    = (f16*)  alloc((size_t)(MAXM+1)*D_*2);

  hipMemsetAsync(cnt, 0, (size_t)M_SEG*4, stream);
  hipMemsetAsync(mcount, 0, 256, stream);
  hipMemsetAsync(abuf, 0, (size_t)D_*2, stream);   // zero-row (abuf slot 0)

  k_hist      <<<(E_+255)/256, 256, 0, stream>>>(ei, et, cnt);
  k_scan_sum  <<<SCAN_BLOCKS, 256, 0, stream>>>(cnt, bsum);
  k_scan_off  <<<1, 256, 0, stream>>>(bsum, boff);
  k_scan_write<<<SCAN_BLOCKS, 256, 0, stream>>>(cnt, boff, row_ptr, cursor);
  k_place     <<<(E_+255)/256, 256, 0, stream>>>(ei, et, cursor, csr_src);
  k_idx       <<<(M_SEG+N_+255)/256, 256, 0, stream>>>(cnt, row_ptr, csr_src, idxT, mp0, mpc, minv, mcount);
  k_gather    <<<(N_+3)/4, 128, 0, stream>>>(node_ids, emb, xA, xA16);
  k_wprep     <<<L_*(R_+1)*D_, 128, 0, stream>>>(comp, basis, root, Wt);

  const int GB = (N_ + GM - 1)/GM;   // 782
  // layer 0: xA -> xB
  k_means<<<4096, 256, 0, stream>>>(xA16, csr_src, mp0, mpc, minv, mcount, abuf);
  k_gemm <<<GB, 256, 0, stream>>>(idxT, xA16, abuf, Wt + (size_t)0*D_*KTOT, xA,
                                  bias+0*D_, gamma+0*D_, beta+0*D_, xB, xB16);
  // layer 1: xB -> xA
  k_means<<<4096, 256, 0, stream>>>(xB16, csr_src, mp0, mpc, minv, mcount, abuf);
  k_gemm <<<GB, 256, 0, stream>>>(idxT, xB16, abuf, Wt + (size_t)1*D_*KTOT, xB,
                                  bias+1*D_, gamma+1*D_, beta+1*D_, xA, xA16);
  // layer 2: xA -> out (x16 to scratch xB16, unused afterwards)
  k_means<<<4096, 256, 0, stream>>>(xA16, csr_src, mp0, mpc, minv, mcount, abuf);
  k_gemm <<<GB, 256, 0, stream>>>(idxT, xA16, abuf, Wt + (size_t)2*D_*KTOT, xA,
                                  bias+2*D_, gamma+2*D_, beta+2*D_, out, xB16);

  k_pool <<<G_, 256, 0, stream>>>(out, batch, out + (size_t)N_*D_);
}